// Round 1
// baseline (124.937 us; speedup 1.0000x reference)
//
#include <hip/hip_runtime.h>
#include <math.h>

#define NK     10000
#define NBATCH 8
#define LSEQ   512
#define KSMAX  11
#define ROWLEN (LSEQ + 2)   // [0]=zero, [1..512]=x, [513]=zero

// ---------------- pass 1: PAD_MAX = max(base) ----------------
__global__ void reduce_max_base(const int* __restrict__ base, int n, int* __restrict__ outv) {
    __shared__ int red[4];
    int tid = threadIdx.x;
    int m = 0;
    for (int i = tid; i < n; i += 256) m = max(m, base[i]);
    #pragma unroll
    for (int off = 32; off > 0; off >>= 1) m = max(m, __shfl_down(m, off));
    if ((tid & 63) == 0) red[tid >> 6] = m;
    __syncthreads();
    if (tid == 0) {
        int r = max(max(red[0], red[1]), max(red[2], red[3]));
        *outv = r;
    }
}

// ---------------- pass 2: main rocket kernel ----------------
template <int KS>
__device__ __forceinline__ void conv_batches(const float* __restrict__ sx,
                                             const float* __restrict__ w, float bi,
                                             int pad, int dl, int lk, int k,
                                             int wave, int lane,
                                             float* __restrict__ out) {
    for (int b = wave; b < NBATCH; b += 4) {
        const float* row = sx + b * ROWLEN;
        float vmax = -INFINITY;
        float vcnt = 0.0f;
        for (int t0 = 0; t0 < lk; t0 += 64) {
            int t = t0 + lane;
            float acc = bi;
            int pos = t - pad;
            #pragma unroll
            for (int j = 0; j < KS; ++j) {
                int pc = min(max(pos, -1), LSEQ) + 1;  // clamp -> zero border
                acc = fmaf(w[j], row[pc], acc);
                pos += dl;
            }
            if (t < lk) {
                vmax = fmaxf(vmax, acc);
                vcnt += (acc > 0.0f) ? 1.0f : 0.0f;
            }
        }
        #pragma unroll
        for (int off = 32; off > 0; off >>= 1) {
            vmax = fmaxf(vmax, __shfl_down(vmax, off));
            vcnt += __shfl_down(vcnt, off);
        }
        if (lane == 0) {
            out[(size_t)b * (2 * NK) + 2 * k]     = vmax;
            out[(size_t)b * (2 * NK) + 2 * k + 1] = vcnt / (float)lk;
        }
    }
}

__global__ __launch_bounds__(256) void rocket_kernel(
    const float* __restrict__ x, const float* __restrict__ W,
    const float* __restrict__ bias, const int* __restrict__ base,
    const int* __restrict__ dil, const int* __restrict__ lo,
    const int* __restrict__ padmax_p, float* __restrict__ out) {
    __shared__ float sx[NBATCH * ROWLEN];
    const int tid = threadIdx.x;
    const int k  = blockIdx.x;

    // stage x -> LDS (8 rows of 512, with a zero slot on each side)
    const float4* x4 = (const float4*)x;
    #pragma unroll
    for (int i = 0; i < 4; ++i) {
        int idx = tid + i * 256;           // float4 index, 0..1023
        float4 v = x4[idx];
        int f = idx * 4;
        int b = f >> 9;                    // /512
        int p = f & 511;
        float* dst = sx + b * ROWLEN + 1 + p;
        dst[0] = v.x; dst[1] = v.y; dst[2] = v.z; dst[3] = v.w;
    }
    if (tid < NBATCH)            sx[tid * ROWLEN] = 0.0f;
    else if (tid < 2 * NBATCH)   sx[(tid - NBATCH) * ROWLEN + LSEQ + 1] = 0.0f;

    // per-kernel params (block-uniform -> scalarized)
    float w[KSMAX];
    #pragma unroll
    for (int j = 0; j < KSMAX; ++j) w[j] = W[(size_t)k * KSMAX + j];
    const float bi = bias[k];
    const int bs = base[k];
    const int dl = dil[k];
    const int lk = lo[k];
    const int pad = *padmax_p - bs;

    __syncthreads();

    const int wave = tid >> 6;
    const int lane = tid & 63;

    // effective kernel size from trailing zero weights (padded rows are exactly 0)
    const bool z7  = (w[7] == 0.0f) && (w[8] == 0.0f) && (w[9] == 0.0f) && (w[10] == 0.0f);
    const bool z9  = (w[9] == 0.0f) && (w[10] == 0.0f);
    if (z7)       conv_batches<7 >(sx, w, bi, pad, dl, lk, k, wave, lane, out);
    else if (z9)  conv_batches<9 >(sx, w, bi, pad, dl, lk, k, wave, lane, out);
    else          conv_batches<11>(sx, w, bi, pad, dl, lk, k, wave, lane, out);
}

extern "C" void kernel_launch(void* const* d_in, const int* in_sizes, int n_in,
                              void* d_out, int out_size, void* d_ws, size_t ws_size,
                              hipStream_t stream) {
    const float* x    = (const float*)d_in[0];
    const float* W    = (const float*)d_in[1];
    const float* bias = (const float*)d_in[2];
    const int*   base = (const int*)d_in[3];
    const int*   dil  = (const int*)d_in[4];
    const int*   lo   = (const int*)d_in[5];
    float* out = (float*)d_out;
    int* padmax = (int*)d_ws;

    reduce_max_base<<<1, 256, 0, stream>>>(base, in_sizes[3], padmax);
    rocket_kernel<<<NK, 256, 0, stream>>>(x, W, bias, base, dil, lo, padmax, out);
}